// Round 1
// 230.164 us; speedup vs baseline: 1.0011x; 1.0011x over previous
//
#include <hip/hip_runtime.h>

// LIF scan over T=8, N=4.2M float4-sites. History:
//  - Rounds 1-7 (prev session): 7 schedules, cached loads, cached or NT
//    stores -> all 87-95 us kernel. Not latency-bound (64KB/CU in-flight
//    didn't move it).
//  - Round 8 (prev session best, 230.2 us harness): NT loads + NT stores
//    -> kernel dropped below the 80 us poison fills (absent from top-5
//    rocprof dispatches). NT LOADS were the lever; stores were NT in both
//    of the last two configs, so (NT-load, cached-store) is untested.
//  - This round: complete the 2x2 -> NT loads + CACHED stores. Theory:
//    cached stores write-allocate in the 256 MiB MALL, so the kernel's
//    HBM side becomes read-only (no per-channel read/write turnaround);
//    the 134 MB dirty drain overlaps the next write-only fill phase.
//    Predict kernel ~70 -> ~50 us, harness 230 -> ~210. If neutral, the
//    NT-both version is at the memory system's service rate => roofline.

typedef float v4f __attribute__((ext_vector_type(4)));

#define DECAY  0.25f
#define THRESH 0.5f

__global__ __launch_bounds__(256) void lif_scan_kernel(
    const v4f* __restrict__ x, v4f* __restrict__ out, int n4) {
    const int i = blockIdx.x * blockDim.x + threadIdx.x;
    if (i >= n4) return;

    const size_t idx = (size_t)i;
    const size_t st  = (size_t)n4;

    v4f m = {0.f, 0.f, 0.f, 0.f};
    v4f s = {0.f, 0.f, 0.f, 0.f};

#pragma unroll
    for (int t = 0; t < 8; ++t) {
        const v4f xv = __builtin_nontemporal_load(&x[idx + (size_t)t * st]);
        m[0] = m[0] * (DECAY * (1.f - s[0])) + xv[0];
        m[1] = m[1] * (DECAY * (1.f - s[1])) + xv[1];
        m[2] = m[2] * (DECAY * (1.f - s[2])) + xv[2];
        m[3] = m[3] * (DECAY * (1.f - s[3])) + xv[3];
        s[0] = (m[0] >= THRESH) ? 1.f : 0.f;
        s[1] = (m[1] >= THRESH) ? 1.f : 0.f;
        s[2] = (m[2] >= THRESH) ? 1.f : 0.f;
        s[3] = (m[3] >= THRESH) ? 1.f : 0.f;
        out[idx + (size_t)t * st] = s;   // cached store: write-allocate in MALL
    }
}

extern "C" void kernel_launch(void* const* d_in, const int* in_sizes, int n_in,
                              void* d_out, int out_size, void* d_ws, size_t ws_size,
                              hipStream_t stream) {
    const float* x = (const float*)d_in[0];
    float* out = (float*)d_out;

    const int total = in_sizes[0];        // 8 * 32 * 128 * 32 * 32 = 33,554,432
    const int T = 8;
    const int n = total / T;              // 4,194,304 sites per timestep
    const int n4 = n / 4;                 // 1,048,576 float4 groups

    const int block = 256;
    const int grid = (n4 + block - 1) / block;  // 4096 blocks

    lif_scan_kernel<<<grid, block, 0, stream>>>(
        (const v4f*)x, (v4f*)out, n4);
}